// Round 1
// baseline (90.855 us; speedup 1.0000x reference)
//
#include <hip/hip_runtime.h>

#define BB 8
#define NN 32
#define SS 8
#define HH 512
#define WW 512
#define KK 9
#define RR 4

// Scatter gaussian stamps for each unique keypoint into bm[B,H,W].
// Dedup: jax .set(1.0) semantics -> duplicate (b,s,y,x) counts once.
__global__ void scatter_gauss(const int* __restrict__ target,
                              const float* __restrict__ gk,
                              float* __restrict__ bm) {
    int idx = blockIdx.x * blockDim.x + threadIdx.x;  // over B*N*S
    if (idx >= BB * NN * SS) return;
    int s = idx % SS;
    int n = (idx / SS) % NN;
    int b = idx / (NN * SS);
    const int* t = target + (((size_t)b * NN + n) * SS + s) * 2;
    int x = t[0], y = t[1];
    // skip if an earlier n' in the same (b,s) group hit the same pixel
    for (int np = 0; np < n; ++np) {
        const int* tp = target + (((size_t)b * NN + np) * SS + s) * 2;
        if (tp[0] == x && tp[1] == y) return;
    }
    float* bmb = bm + (size_t)b * HH * WW;
    for (int dy = -RR; dy <= RR; ++dy) {
        int yy = y + dy;
        if (yy < 0 || yy >= HH) continue;
        for (int dx = -RR; dx <= RR; ++dx) {
            int xx = x + dx;
            if (xx < 0 || xx >= WW) continue;
            // kernel is symmetric, so gk[dy+R][dx+R] == gk[R-dy][R-dx]
            atomicAdd(&bmb[yy * WW + xx], gk[(dy + RR) * KK + (dx + RR)]);
        }
    }
}

// Fused MSE: sum over (b,s,h,w) of (pred - bm[b,h,w])^2, float4 vectorized.
__global__ void reduce_loss(const float* __restrict__ pred,
                            const float* __restrict__ bm,
                            double* __restrict__ acc) {
    const int total4 = BB * HH * WW / 4;  // 524288
    float local = 0.f;
    for (int i = blockIdx.x * blockDim.x + threadIdx.x; i < total4;
         i += gridDim.x * blockDim.x) {
        int b = i / (HH * WW / 4);
        int hw4 = i % (HH * WW / 4);
        float4 bmv = ((const float4*)bm)[i];
        const float* pb = pred + (size_t)b * SS * HH * WW;
#pragma unroll
        for (int s = 0; s < SS; ++s) {
            float4 p = ((const float4*)(pb + (size_t)s * HH * WW))[hw4];
            float d0 = p.x - bmv.x;
            float d1 = p.y - bmv.y;
            float d2 = p.z - bmv.z;
            float d3 = p.w - bmv.w;
            local += d0 * d0 + d1 * d1 + d2 * d2 + d3 * d3;
        }
    }
    // wave(64) shuffle reduce
    for (int off = 32; off; off >>= 1) local += __shfl_down(local, off);
    __shared__ float warp_s[4];
    int lane = threadIdx.x & 63, wid = threadIdx.x >> 6;
    if (lane == 0) warp_s[wid] = local;
    __syncthreads();
    if (threadIdx.x == 0) {
        float blk = warp_s[0] + warp_s[1] + warp_s[2] + warp_s[3];
        atomicAdd(acc, (double)blk);
    }
}

__global__ void finalize(const double* __restrict__ acc, float* __restrict__ out) {
    out[0] = (float)(acc[0] / (double)((size_t)BB * SS * HH * WW));
}

extern "C" void kernel_launch(void* const* d_in, const int* in_sizes, int n_in,
                              void* d_out, int out_size, void* d_ws, size_t ws_size,
                              hipStream_t stream) {
    const float* pred = (const float*)d_in[0];     // (B,S,H,W) f32
    const int* target = (const int*)d_in[1];       // (B,N,S,2) i32
    const float* gk   = (const float*)d_in[2];     // (9,9) f32

    float* bm   = (float*)d_ws;                                   // B*H*W f32 = 8 MB
    double* acc = (double*)((char*)d_ws + (size_t)BB * HH * WW * 4);  // 8B, aligned

    hipMemsetAsync(d_ws, 0, (size_t)BB * HH * WW * 4 + 8, stream);

    scatter_gauss<<<(BB * NN * SS + 255) / 256, 256, 0, stream>>>(target, gk, bm);
    reduce_loss<<<2048, 256, 0, stream>>>(pred, bm, acc);
    finalize<<<1, 1, 0, stream>>>(acc, (float*)d_out);
}

// Round 2
// 34.038 us; speedup vs baseline: 2.6693x; 2.6693x over previous
//
#include <hip/hip_runtime.h>

#define BB 8
#define NN 32
#define SS 8
#define HH 512
#define WW 512
#define KK 9
#define RR 4
#define NKP (BB * NN * SS)          // 2048 keypoints
#define NTAP (KK * KK)              // 81 taps per stamp
#define RBLOCKS 1024                // reduce grid

// One thread per (keypoint, tap): dedup-check the keypoint, then one atomicAdd.
__global__ void scatter_gauss(const int* __restrict__ target,
                              const float* __restrict__ gk,
                              float* __restrict__ bm) {
    int idx = blockIdx.x * blockDim.x + threadIdx.x;  // over NKP*NTAP
    if (idx >= NKP * NTAP) return;
    int tap = idx % NTAP;
    int kp = idx / NTAP;
    int s = kp % SS;
    int n = (kp / SS) % NN;
    int b = kp / (NN * SS);
    const int* t = target + ((size_t)kp) * 2;
    int x = t[0], y = t[1];
    // jax .set(1.0) semantics: duplicate (b,s,y,x) counts once -> skip if an
    // earlier n' in the same (b,s) group hit the same pixel (target is 16 KB,
    // fully L2-cached; scan is cheap).
    for (int np = 0; np < n; ++np) {
        const int* tp = target + (((size_t)b * NN + np) * SS + s) * 2;
        if (tp[0] == x && tp[1] == y) return;
    }
    int dy = tap / KK - RR;
    int dx = tap % KK - RR;
    int yy = y + dy, xx = x + dx;
    if (yy < 0 || yy >= HH || xx < 0 || xx >= WW) return;
    atomicAdd(&bm[(size_t)b * HH * WW + yy * WW + xx], gk[tap]);
}

// Fused MSE partial sums: (pred - bm)^2 over (b,s,h,w); one double per block.
__global__ void reduce_loss(const float* __restrict__ pred,
                            const float* __restrict__ bm,
                            double* __restrict__ partial) {
    const int total4 = BB * HH * WW / 4;  // 524288 float4 positions of bm
    float local = 0.f;
    for (int i = blockIdx.x * blockDim.x + threadIdx.x; i < total4;
         i += gridDim.x * blockDim.x) {
        int b = i / (HH * WW / 4);
        int hw4 = i % (HH * WW / 4);
        float4 bmv = ((const float4*)bm)[i];
        const float* pb = pred + (size_t)b * SS * HH * WW;
#pragma unroll
        for (int s = 0; s < SS; ++s) {
            float4 p = ((const float4*)(pb + (size_t)s * HH * WW))[hw4];
            float d0 = p.x - bmv.x;
            float d1 = p.y - bmv.y;
            float d2 = p.z - bmv.z;
            float d3 = p.w - bmv.w;
            local += d0 * d0 + d1 * d1 + d2 * d2 + d3 * d3;
        }
    }
    // wave(64) shuffle reduce -> per-block partial (no global atomics)
    for (int off = 32; off; off >>= 1) local += __shfl_down(local, off);
    __shared__ float warp_s[4];
    int lane = threadIdx.x & 63, wid = threadIdx.x >> 6;
    if (lane == 0) warp_s[wid] = local;
    __syncthreads();
    if (threadIdx.x == 0)
        partial[blockIdx.x] = (double)(warp_s[0] + warp_s[1] + warp_s[2] + warp_s[3]);
}

// Single block: sum RBLOCKS doubles, write the mean.
__global__ void final_reduce(const double* __restrict__ partial,
                             float* __restrict__ out) {
    double local = 0.0;
    for (int i = threadIdx.x; i < RBLOCKS; i += 256) local += partial[i];
    for (int off = 32; off; off >>= 1) local += __shfl_down(local, off);
    __shared__ double warp_s[4];
    int lane = threadIdx.x & 63, wid = threadIdx.x >> 6;
    if (lane == 0) warp_s[wid] = local;
    __syncthreads();
    if (threadIdx.x == 0) {
        double sum = warp_s[0] + warp_s[1] + warp_s[2] + warp_s[3];
        out[0] = (float)(sum / (double)((size_t)BB * SS * HH * WW));
    }
}

extern "C" void kernel_launch(void* const* d_in, const int* in_sizes, int n_in,
                              void* d_out, int out_size, void* d_ws, size_t ws_size,
                              hipStream_t stream) {
    const float* pred = (const float*)d_in[0];     // (B,S,H,W) f32
    const int* target = (const int*)d_in[1];       // (B,N,S,2) i32
    const float* gk   = (const float*)d_in[2];     // (9,9) f32

    float* bm       = (float*)d_ws;                                   // 8 MB
    double* partial = (double*)((char*)d_ws + (size_t)BB * HH * WW * 4);

    hipMemsetAsync(d_ws, 0, (size_t)BB * HH * WW * 4, stream);

    scatter_gauss<<<(NKP * NTAP + 255) / 256, 256, 0, stream>>>(target, gk, bm);
    reduce_loss<<<RBLOCKS, 256, 0, stream>>>(pred, bm, partial);
    final_reduce<<<1, 256, 0, stream>>>(partial, (float*)d_out);
}

// Round 3
// 33.137 us; speedup vs baseline: 2.7418x; 1.0272x over previous
//
#include <hip/hip_runtime.h>

#define BB 8
#define NN 32
#define SS 8
#define HH 512
#define WW 512
#define KK 9
#define RR 4
#define NKP (BB * NN * SS)          // 2048 keypoints
#define NTAP (KK * KK)              // 81 taps per stamp
#define RBLOCKS 1024                // reduce grid

// Zero the 8 MB belive-map: one float4 per thread, 2048 blocks. The runtime's
// fillBufferAligned ran at 206 GB/s (40.9 us); this should be ~2 us.
__global__ void zero_bm(float4* __restrict__ bm4) {
    int i = blockIdx.x * blockDim.x + threadIdx.x;  // 524288 float4s
    bm4[i] = make_float4(0.f, 0.f, 0.f, 0.f);
}

// One thread per (keypoint, tap): dedup-check the keypoint, then one atomicAdd.
__global__ void scatter_gauss(const int* __restrict__ target,
                              const float* __restrict__ gk,
                              float* __restrict__ bm) {
    int idx = blockIdx.x * blockDim.x + threadIdx.x;  // over NKP*NTAP
    if (idx >= NKP * NTAP) return;
    int tap = idx % NTAP;
    int kp = idx / NTAP;
    int s = kp % SS;
    int n = (kp / SS) % NN;
    int b = kp / (NN * SS);
    const int* t = target + ((size_t)kp) * 2;
    int x = t[0], y = t[1];
    // jax .set(1.0) semantics: duplicate (b,s,y,x) counts once -> skip if an
    // earlier n' in the same (b,s) group hit the same pixel (target is 16 KB,
    // fully L2-cached; scan is cheap).
    for (int np = 0; np < n; ++np) {
        const int* tp = target + (((size_t)b * NN + np) * SS + s) * 2;
        if (tp[0] == x && tp[1] == y) return;
    }
    int dy = tap / KK - RR;
    int dx = tap % KK - RR;
    int yy = y + dy, xx = x + dx;
    if (yy < 0 || yy >= HH || xx < 0 || xx >= WW) return;
    atomicAdd(&bm[(size_t)b * HH * WW + yy * WW + xx], gk[tap]);
}

// Fused MSE partial sums: (pred - bm)^2 over (b,s,h,w); one double per block.
__global__ void reduce_loss(const float* __restrict__ pred,
                            const float* __restrict__ bm,
                            double* __restrict__ partial) {
    const int total4 = BB * HH * WW / 4;  // 524288 float4 positions of bm
    float local = 0.f;
    for (int i = blockIdx.x * blockDim.x + threadIdx.x; i < total4;
         i += gridDim.x * blockDim.x) {
        int b = i / (HH * WW / 4);
        int hw4 = i % (HH * WW / 4);
        float4 bmv = ((const float4*)bm)[i];
        const float* pb = pred + (size_t)b * SS * HH * WW;
#pragma unroll
        for (int s = 0; s < SS; ++s) {
            float4 p = ((const float4*)(pb + (size_t)s * HH * WW))[hw4];
            float d0 = p.x - bmv.x;
            float d1 = p.y - bmv.y;
            float d2 = p.z - bmv.z;
            float d3 = p.w - bmv.w;
            local += d0 * d0 + d1 * d1 + d2 * d2 + d3 * d3;
        }
    }
    // wave(64) shuffle reduce -> per-block partial (no global atomics)
    for (int off = 32; off; off >>= 1) local += __shfl_down(local, off);
    __shared__ float warp_s[4];
    int lane = threadIdx.x & 63, wid = threadIdx.x >> 6;
    if (lane == 0) warp_s[wid] = local;
    __syncthreads();
    if (threadIdx.x == 0)
        partial[blockIdx.x] = (double)(warp_s[0] + warp_s[1] + warp_s[2] + warp_s[3]);
}

// Single block: sum RBLOCKS doubles, write the mean.
__global__ void final_reduce(const double* __restrict__ partial,
                             float* __restrict__ out) {
    double local = 0.0;
    for (int i = threadIdx.x; i < RBLOCKS; i += 256) local += partial[i];
    for (int off = 32; off; off >>= 1) local += __shfl_down(local, off);
    __shared__ double warp_s[4];
    int lane = threadIdx.x & 63, wid = threadIdx.x >> 6;
    if (lane == 0) warp_s[wid] = local;
    __syncthreads();
    if (threadIdx.x == 0) {
        double sum = warp_s[0] + warp_s[1] + warp_s[2] + warp_s[3];
        out[0] = (float)(sum / (double)((size_t)BB * SS * HH * WW));
    }
}

extern "C" void kernel_launch(void* const* d_in, const int* in_sizes, int n_in,
                              void* d_out, int out_size, void* d_ws, size_t ws_size,
                              hipStream_t stream) {
    const float* pred = (const float*)d_in[0];     // (B,S,H,W) f32
    const int* target = (const int*)d_in[1];       // (B,N,S,2) i32
    const float* gk   = (const float*)d_in[2];     // (9,9) f32

    float* bm       = (float*)d_ws;                                   // 8 MB
    double* partial = (double*)((char*)d_ws + (size_t)BB * HH * WW * 4);

    zero_bm<<<(BB * HH * WW / 4) / 256, 256, 0, stream>>>((float4*)bm);
    scatter_gauss<<<(NKP * NTAP + 255) / 256, 256, 0, stream>>>(target, gk, bm);
    reduce_loss<<<RBLOCKS, 256, 0, stream>>>(pred, bm, partial);
    final_reduce<<<1, 256, 0, stream>>>(partial, (float*)d_out);
}